// Round 2
// baseline (2037.236 us; speedup 1.0000x reference)
//
#include <hip/hip_runtime.h>
#include <hip/hip_bf16.h>
#include <math.h>

// ---------------------------------------------------------------------------
// WaveNet inference, fp32, right-aligned suffix computation.
// Key derivations:
//  - dilate() batch-folding == time-domain dilated 2-tap conv, out[t] uses
//    taps X[t], X[t+d]; residual adds X[t+d]; front-padding in dilate() only
//    ever touches the LEFT edge, never the right-aligned suffix we need.
//  - x_skip is OVERWRITTEN each layer -> only layer 39's skip matters, and
//    its input is h = tanh*sigmoid (BEFORE the residual conv).  <- r1 fix
//  - output needs only the trailing 4096+4092=8188 samples of start conv.
// ---------------------------------------------------------------------------

#define TS   8192      // time stride of activation rows (max needed 8188)
#define T0   8188      // trailing samples of start-conv output
#define NB   8
#define RCH  32
#define SCH  256
#define ECH  256
#define CLS  256
#define TOUT 4096

// workspace layout (float offsets)
#define OFF_WBLOB 0                      // 40 * 5120  (wf[ic][k][oc], wg, wr[ic][oc])
#define OFF_ST    204800                 // start_w^T  [ic][oc]        (256*32)
#define OFF_SK    212992                 // skip_w[39]^T [dc][sc]      (32*256)
#define OFF_E1T   221184                 // end1_w^T [sc][ec]          (256*256)
#define OFF_E2T   286720                 // end2_w^T [ec][cc]          (256*256)
#define OFF_XA    352256                 // NB*RCH*TS
#define OFF_XB    (OFF_XA + NB*RCH*TS)
#define OFF_H1    (OFF_XB + NB*RCH*TS)   // NB*SCH*TOUT
#define OFF_E1    (OFF_H1 + NB*SCH*TOUT)
// total = OFF_E1 + NB*ECH*TOUT = 21323776 floats = ~85.3 MB of d_ws

__device__ __forceinline__ float tanh_fast(float x) {
    float e = __expf(2.0f * x);
    return 1.0f - 2.0f / (e + 1.0f);   // safe at +/-inf
}
__device__ __forceinline__ float sigmoid_fast(float x) {
    return 1.0f / (1.0f + __expf(-x));
}

// ---------------------------------------------------------------------------
__global__ void repack_kernel(const float* __restrict__ start_w,
                              const float* __restrict__ filter_w,
                              const float* __restrict__ gate_w,
                              const float* __restrict__ residual_w,
                              const float* __restrict__ skip_w,
                              const float* __restrict__ end1_w,
                              const float* __restrict__ end2_w,
                              float* __restrict__ ws) {
    int id = blockIdx.x * 256 + threadIdx.x;
    if (id < 204800) {                       // per-layer blob
        int l = id / 5120, r = id % 5120;
        float v;
        if (r < 4096) {                      // wf then wg: [ic][k][oc]
            const float* src = (r < 2048) ? filter_w : gate_w;
            int rr = r & 2047;
            int ic = rr >> 6, k = (rr >> 5) & 1, oc = rr & 31;
            v = src[((l * 32 + oc) * 32 + ic) * 2 + k];
        } else {                             // wr: [ic][oc]
            int rr = r - 4096;
            int ic = rr >> 5, oc = rr & 31;
            v = residual_w[(l * 32 + oc) * 32 + ic];
        }
        ws[OFF_WBLOB + id] = v;
    } else if (id < 204800 + 8192) {         // start_w^T [ic][oc]
        int r = id - 204800;
        int ic = r >> 5, oc = r & 31;
        ws[OFF_ST + r] = start_w[oc * 256 + ic];
    } else if (id < 212992 + 8192) {         // skip_w[39]^T [dc][sc]
        int r = id - 212992;
        int dc = r >> 8, sc = r & 255;
        ws[OFF_SK + r] = skip_w[(39 * 256 + sc) * 32 + dc];
    } else if (id < 221184 + 65536) {        // end1^T [sc][ec]
        int r = id - 221184;
        int sc = r >> 8, ec = r & 255;
        ws[OFF_E1T + r] = end1_w[ec * 256 + sc];
    } else if (id < 286720 + 65536) {        // end2^T [ec][cc]
        int r = id - 286720;
        int ec = r >> 8, cc = r & 255;
        ws[OFF_E2T + r] = end2_w[cc * 256 + ec];
    }
}

// ---------------------------------------------------------------------------
// start conv: x0[b][c][t] = sum_ic st[ic][c] * x_input[b][ic][16384-T0+t]
__global__ __launch_bounds__(256) void start_kernel(const float* __restrict__ xin,
                                                    const float* __restrict__ st,
                                                    float* __restrict__ xout) {
    int t = blockIdx.x * 256 + threadIdx.x;
    int b = blockIdx.y;
    if (t >= T0) return;
    const float* xi = xin + (size_t)b * 256 * 16384 + (16384 - T0) + t;
    float acc[32];
#pragma unroll
    for (int c = 0; c < 32; c++) acc[c] = 0.f;
    for (int ic = 0; ic < 256; ic++) {
        float xv = xi[ic * 16384];
        const float* w = st + ic * 32;       // uniform -> s_load
#pragma unroll
        for (int c = 0; c < 32; c++) acc[c] = fmaf(w[c], xv, acc[c]);
    }
    float* xo = xout + (size_t)(b * RCH) * TS + t;
#pragma unroll
    for (int c = 0; c < 32; c++) xo[c * TS] = acc[c];
}

// ---------------------------------------------------------------------------
// one WaveNet layer, fused: 2-tap dilated conv (filter+gate) -> tanh*sigmoid
// -> 1x1 residual conv + shifted input.  out[t] uses in[t], in[t+d].
__global__ __launch_bounds__(256) void layer_kernel(const float* __restrict__ xin,
                                                    float* __restrict__ xout,
                                                    const float* __restrict__ wl,
                                                    int d, int Tout) {
    int t = blockIdx.x * 256 + threadIdx.x;
    int b = blockIdx.y;
    if (t >= Tout) return;
    const float* xi = xin + (size_t)(b * RCH) * TS + t;
    const float* wf = wl;
    const float* wg = wl + 2048;
    const float* wr = wl + 4096;

    float accf[32], accg[32];
#pragma unroll
    for (int o = 0; o < 32; o++) { accf[o] = 0.f; accg[o] = 0.f; }

#pragma unroll 2
    for (int ic = 0; ic < 32; ic++) {
        float a = xi[ic * TS];
        float c = xi[ic * TS + d];
        const float* w0 = wf + ic * 64;      // uniform -> s_load
        const float* w1 = wg + ic * 64;
#pragma unroll
        for (int o = 0; o < 32; o++) accf[o] = fmaf(w0[o],      a, accf[o]);
#pragma unroll
        for (int o = 0; o < 32; o++) accf[o] = fmaf(w0[32 + o], c, accf[o]);
#pragma unroll
        for (int o = 0; o < 32; o++) accg[o] = fmaf(w1[o],      a, accg[o]);
#pragma unroll
        for (int o = 0; o < 32; o++) accg[o] = fmaf(w1[32 + o], c, accg[o]);
    }

    float h[32];
#pragma unroll
    for (int o = 0; o < 32; o++) h[o] = tanh_fast(accf[o]) * sigmoid_fast(accg[o]);

    float accr[32];
#pragma unroll
    for (int o = 0; o < 32; o++) accr[o] = xi[o * TS + d];   // residual: X[t+d]
#pragma unroll
    for (int ic = 0; ic < 32; ic++) {
        const float* w = wr + ic * 32;
        float hv = h[ic];
#pragma unroll
        for (int o = 0; o < 32; o++) accr[o] = fmaf(w[o], hv, accr[o]);
    }

    float* xo = xout + (size_t)(b * RCH) * TS + t;
#pragma unroll
    for (int o = 0; o < 32; o++) xo[o * TS] = accr[o];
}

// ---------------------------------------------------------------------------
// LAST layer (i=39): the only consumer is the skip conv, whose input is
// h = tanh*sigmoid (NOT the residual output).  Residual path is dead code.
__global__ __launch_bounds__(256) void layer_last_kernel(const float* __restrict__ xin,
                                                         float* __restrict__ xout,
                                                         const float* __restrict__ wl,
                                                         int d, int Tout) {
    int t = blockIdx.x * 256 + threadIdx.x;
    int b = blockIdx.y;
    if (t >= Tout) return;
    const float* xi = xin + (size_t)(b * RCH) * TS + t;
    const float* wf = wl;
    const float* wg = wl + 2048;

    float accf[32], accg[32];
#pragma unroll
    for (int o = 0; o < 32; o++) { accf[o] = 0.f; accg[o] = 0.f; }

#pragma unroll 2
    for (int ic = 0; ic < 32; ic++) {
        float a = xi[ic * TS];
        float c = xi[ic * TS + d];
        const float* w0 = wf + ic * 64;
        const float* w1 = wg + ic * 64;
#pragma unroll
        for (int o = 0; o < 32; o++) accf[o] = fmaf(w0[o],      a, accf[o]);
#pragma unroll
        for (int o = 0; o < 32; o++) accf[o] = fmaf(w0[32 + o], c, accf[o]);
#pragma unroll
        for (int o = 0; o < 32; o++) accg[o] = fmaf(w1[o],      a, accg[o]);
#pragma unroll
        for (int o = 0; o < 32; o++) accg[o] = fmaf(w1[32 + o], c, accg[o]);
    }

    float* xo = xout + (size_t)(b * RCH) * TS + t;
#pragma unroll
    for (int o = 0; o < 32; o++)
        xo[o * TS] = tanh_fast(accf[o]) * sigmoid_fast(accg[o]);
}

// ---------------------------------------------------------------------------
// skip conv + relu: h1[b][sc][t] = relu(sum_dc sk[dc][sc] * h[b][dc][t])
__global__ __launch_bounds__(256) void skip_kernel(const float* __restrict__ xin,
                                                   const float* __restrict__ sk,
                                                   float* __restrict__ h1) {
    int t = blockIdx.x * 256 + threadIdx.x;
    int scg = blockIdx.y;                    // 4 groups of 64
    int b = blockIdx.z;
    const float* xi = xin + (size_t)(b * RCH) * TS + t;
    float acc[64];
#pragma unroll
    for (int j = 0; j < 64; j++) acc[j] = 0.f;
    for (int dc = 0; dc < 32; dc++) {
        float xv = xi[dc * TS];
        const float* w = sk + dc * 256 + scg * 64;
#pragma unroll
        for (int j = 0; j < 64; j++) acc[j] = fmaf(w[j], xv, acc[j]);
    }
    float* ho = h1 + ((size_t)(b * 256) + scg * 64) * TOUT + t;
#pragma unroll
    for (int j = 0; j < 64; j++) ho[j * TOUT] = fmaxf(acc[j], 0.f);
}

// end1 + bias + relu
__global__ __launch_bounds__(256) void end1_kernel(const float* __restrict__ h1,
                                                   const float* __restrict__ e1t,
                                                   const float* __restrict__ b1,
                                                   float* __restrict__ e1) {
    int t = blockIdx.x * 256 + threadIdx.x;
    int eg = blockIdx.y;
    int b = blockIdx.z;
    const float* hp = h1 + (size_t)(b * 256) * TOUT + t;
    float acc[64];
#pragma unroll
    for (int j = 0; j < 64; j++) acc[j] = b1[eg * 64 + j];
    for (int sc = 0; sc < 256; sc++) {
        float xv = hp[sc * TOUT];
        const float* w = e1t + sc * 256 + eg * 64;
#pragma unroll
        for (int j = 0; j < 64; j++) acc[j] = fmaf(w[j], xv, acc[j]);
    }
    float* ep = e1 + ((size_t)(b * 256) + eg * 64) * TOUT + t;
#pragma unroll
    for (int j = 0; j < 64; j++) ep[j * TOUT] = fmaxf(acc[j], 0.f);
}

// end2 + bias, store transposed: out[(b*4096+t)*256 + cc]
__global__ __launch_bounds__(256) void end2_kernel(const float* __restrict__ e1,
                                                   const float* __restrict__ e2t,
                                                   const float* __restrict__ b2,
                                                   float* __restrict__ out) {
    int t = blockIdx.x * 256 + threadIdx.x;
    int cg = blockIdx.y;
    int b = blockIdx.z;
    const float* ep = e1 + (size_t)(b * 256) * TOUT + t;
    float acc[64];
#pragma unroll
    for (int j = 0; j < 64; j++) acc[j] = b2[cg * 64 + j];
    for (int ec = 0; ec < 256; ec++) {
        float xv = ep[ec * TOUT];
        const float* w = e2t + ec * 256 + cg * 64;
#pragma unroll
        for (int j = 0; j < 64; j++) acc[j] = fmaf(w[j], xv, acc[j]);
    }
    float* op = out + ((size_t)(b * TOUT + t)) * CLS + cg * 64;
#pragma unroll
    for (int j = 0; j < 16; j++)
        ((float4*)op)[j] = make_float4(acc[4*j], acc[4*j+1], acc[4*j+2], acc[4*j+3]);
}

// ---------------------------------------------------------------------------
extern "C" void kernel_launch(void* const* d_in, const int* in_sizes, int n_in,
                              void* d_out, int out_size, void* d_ws, size_t ws_size,
                              hipStream_t stream) {
    const float* x_input    = (const float*)d_in[0];
    const float* start_w    = (const float*)d_in[1];
    const float* filter_w   = (const float*)d_in[2];
    const float* gate_w     = (const float*)d_in[3];
    const float* residual_w = (const float*)d_in[4];
    const float* skip_w     = (const float*)d_in[5];
    const float* end1_w     = (const float*)d_in[6];
    const float* end1_b     = (const float*)d_in[7];
    const float* end2_w     = (const float*)d_in[8];
    const float* end2_b     = (const float*)d_in[9];
    float* ws  = (float*)d_ws;
    float* out = (float*)d_out;

    repack_kernel<<<dim3((352256 + 255) / 256), 256, 0, stream>>>(
        start_w, filter_w, gate_w, residual_w, skip_w, end1_w, end2_w, ws);

    start_kernel<<<dim3((T0 + 255) / 256, NB), 256, 0, stream>>>(
        x_input, ws + OFF_ST, ws + OFF_XA);

    float* bufs[2] = { ws + OFF_XA, ws + OFF_XB };
    int cur = 0;
    int Tin = T0;
    int cnt = 0;
    for (int bl = 0; bl < 4; bl++) {
        int dd = 1;
        for (int i = 0; i < 10; i++) {
            int Tout_l = Tin - dd;
            if (cnt < 39) {
                layer_kernel<<<dim3((Tout_l + 255) / 256, NB), 256, 0, stream>>>(
                    bufs[cur], bufs[cur ^ 1], ws + OFF_WBLOB + (size_t)cnt * 5120, dd, Tout_l);
            } else {
                layer_last_kernel<<<dim3((Tout_l + 255) / 256, NB), 256, 0, stream>>>(
                    bufs[cur], bufs[cur ^ 1], ws + OFF_WBLOB + (size_t)cnt * 5120, dd, Tout_l);
            }
            cur ^= 1;
            Tin = Tout_l;
            dd *= 2;
            cnt++;
        }
    }
    // Tin == 4096 here; h of layer 39 in bufs[cur]

    skip_kernel<<<dim3(16, 4, NB), 256, 0, stream>>>(bufs[cur], ws + OFF_SK, ws + OFF_H1);
    end1_kernel<<<dim3(16, 4, NB), 256, 0, stream>>>(ws + OFF_H1, ws + OFF_E1T, end1_b, ws + OFF_E1);
    end2_kernel<<<dim3(16, 4, NB), 256, 0, stream>>>(ws + OFF_E1, ws + OFF_E2T, end2_b, out);
}

// Round 3
// 910.120 us; speedup vs baseline: 2.2384x; 2.2384x over previous
//
#include <hip/hip_runtime.h>
#include <hip/hip_bf16.h>
#include <math.h>

// ---------------------------------------------------------------------------
// WaveNet inference, fp32, right-aligned suffix computation.
// Derivations (verified round 2, absmax 2.4e-4):
//  - dilate() batch-folding == time-domain dilated 2-tap conv: out[t] uses
//    taps X[t], X[t+d]; residual adds X[t+d].
//  - x_skip is OVERWRITTEN each layer -> only layer 39's skip matters, and
//    its input is h = tanh*sigmoid (BEFORE the residual conv).
//  - output needs only the trailing 4096+4092=8188 samples of start conv.
// Round 3: occupancy fixes. Layer: 4 threads/timestep (8 ch each), h via
// LDS; waves/CU 4->16. End GEMMs: 32 out/thread, waves/CU 8->16.
// ---------------------------------------------------------------------------

#define TS   8192
#define T0   8188
#define NB   8
#define RCH  32
#define CLS  256
#define TOUT 4096

// workspace layout (float offsets)
#define OFF_WBLOB 0                      // 40 * 5120  (wf[ic][k][oc], wg, wr[ic][oc])
#define OFF_ST    204800                 // start_w^T  [ic][oc]
#define OFF_SK    212992                 // skip_w[39]^T [dc][sc]
#define OFF_E1T   221184                 // end1^T [sc][ec]
#define OFF_E2T   286720                 // end2^T [ec][cc]
#define OFF_XA    352256                 // NB*RCH*TS
#define OFF_XB    (OFF_XA + NB*RCH*TS)
#define OFF_H1    (OFF_XB + NB*RCH*TS)   // NB*256*TOUT
#define OFF_E1    (OFF_H1 + NB*256*TOUT)

__device__ __forceinline__ float tanh_fast(float x) {
    float e = __expf(2.0f * x);
    return 1.0f - 2.0f / (e + 1.0f);
}
__device__ __forceinline__ float sigmoid_fast(float x) {
    return 1.0f / (1.0f + __expf(-x));
}

// ---------------------------------------------------------------------------
__global__ void repack_kernel(const float* __restrict__ start_w,
                              const float* __restrict__ filter_w,
                              const float* __restrict__ gate_w,
                              const float* __restrict__ residual_w,
                              const float* __restrict__ skip_w,
                              const float* __restrict__ end1_w,
                              const float* __restrict__ end2_w,
                              float* __restrict__ ws) {
    int id = blockIdx.x * 256 + threadIdx.x;
    if (id < 204800) {
        int l = id / 5120, r = id % 5120;
        float v;
        if (r < 4096) {                      // wf then wg: [ic][k][oc]
            const float* src = (r < 2048) ? filter_w : gate_w;
            int rr = r & 2047;
            int ic = rr >> 6, k = (rr >> 5) & 1, oc = rr & 31;
            v = src[((l * 32 + oc) * 32 + ic) * 2 + k];
        } else {                             // wr: [ic][oc]
            int rr = r - 4096;
            int ic = rr >> 5, oc = rr & 31;
            v = residual_w[(l * 32 + oc) * 32 + ic];
        }
        ws[OFF_WBLOB + id] = v;
    } else if (id < 204800 + 8192) {
        int r = id - 204800;
        int ic = r >> 5, oc = r & 31;
        ws[OFF_ST + r] = start_w[oc * 256 + ic];
    } else if (id < 212992 + 8192) {
        int r = id - 212992;
        int dc = r >> 8, sc = r & 255;
        ws[OFF_SK + r] = skip_w[(39 * 256 + sc) * 32 + dc];
    } else if (id < 221184 + 65536) {
        int r = id - 221184;
        int sc = r >> 8, ec = r & 255;
        ws[OFF_E1T + r] = end1_w[ec * 256 + sc];
    } else if (id < 286720 + 65536) {
        int r = id - 286720;
        int ec = r >> 8, cc = r & 255;
        ws[OFF_E2T + r] = end2_w[cc * 256 + ec];
    }
}

// ---------------------------------------------------------------------------
// start conv, 16 outputs/thread: 2048 waves (8/CU)
__global__ __launch_bounds__(256) void start_kernel(const float* __restrict__ xin,
                                                    const float* __restrict__ st,
                                                    float* __restrict__ xout) {
    int t = blockIdx.x * 256 + threadIdx.x;
    int og = blockIdx.y;                     // 0..1 (16 oc each)
    int b = blockIdx.z;
    if (t >= T0) return;
    const float* xi = xin + (size_t)b * 256 * 16384 + (16384 - T0) + t;
    const float* wb = st + og * 16;
    float acc[16];
#pragma unroll
    for (int c = 0; c < 16; c++) acc[c] = 0.f;
#pragma unroll 4
    for (int ic = 0; ic < 256; ic++) {
        float xv = xi[ic * 16384];
        const float* w = wb + ic * 32;
#pragma unroll
        for (int c = 0; c < 16; c++) acc[c] = fmaf(w[c], xv, acc[c]);
    }
    float* xo = xout + ((size_t)(b * RCH) + og * 16) * TS + t;
#pragma unroll
    for (int c = 0; c < 16; c++) xo[c * TS] = acc[c];
}

// ---------------------------------------------------------------------------
// one WaveNet layer, block (64,4): 4 threads per timestep, 8 channels each.
// h exchanged via LDS (bank = t%32, 2-way across 64 lanes = conflict-free).
__global__ __launch_bounds__(256) void layer_kernel(const float* __restrict__ xin,
                                                    float* __restrict__ xout,
                                                    const float* __restrict__ wl,
                                                    int d, int Tout) {
    __shared__ float hs[32][64];
    int tx = threadIdx.x;                        // 0..63 = lane
    int cg = __builtin_amdgcn_readfirstlane(threadIdx.y);  // wave-uniform -> s_load weights
    int t  = blockIdx.x * 64 + tx;
    int b  = blockIdx.y;
    bool act = (t < Tout);

    const float* xi = xin + (size_t)(b * RCH) * TS + t;
    const float* wf = wl +        cg * 8;    // wf[ic*64 + k*32 + oc8]
    const float* wg = wl + 2048 + cg * 8;
    const float* wr = wl + 4096 + cg * 8;    // wr[ic*32 + oc8]

    float accf[8], accg[8];
#pragma unroll
    for (int j = 0; j < 8; j++) { accf[j] = 0.f; accg[j] = 0.f; }

#pragma unroll 4
    for (int ic = 0; ic < 32; ic++) {
        float a = xi[ic * TS];
        float c = xi[ic * TS + d];
        const float* w0 = wf + ic * 64;
        const float* w1 = wg + ic * 64;
#pragma unroll
        for (int j = 0; j < 8; j++) accf[j] = fmaf(w0[j],      a, accf[j]);
#pragma unroll
        for (int j = 0; j < 8; j++) accf[j] = fmaf(w0[32 + j], c, accf[j]);
#pragma unroll
        for (int j = 0; j < 8; j++) accg[j] = fmaf(w1[j],      a, accg[j]);
#pragma unroll
        for (int j = 0; j < 8; j++) accg[j] = fmaf(w1[32 + j], c, accg[j]);
    }

#pragma unroll
    for (int j = 0; j < 8; j++)
        hs[cg * 8 + j][tx] = tanh_fast(accf[j]) * sigmoid_fast(accg[j]);
    __syncthreads();

    float accr[8];
#pragma unroll
    for (int j = 0; j < 8; j++) accr[j] = xi[(cg * 8 + j) * TS + d];  // residual X[t+d]
#pragma unroll 4
    for (int ic = 0; ic < 32; ic++) {
        float h = hs[ic][tx];
        const float* w = wr + ic * 32;
#pragma unroll
        for (int j = 0; j < 8; j++) accr[j] = fmaf(w[j], h, accr[j]);
    }

    if (act) {
        float* xo = xout + ((size_t)(b * RCH) + cg * 8) * TS + t;
#pragma unroll
        for (int j = 0; j < 8; j++) xo[j * TS] = accr[j];
    }
}

// ---------------------------------------------------------------------------
// LAST layer (i=39): only h = tanh*sigmoid is consumed (skip conv input).
// No channel mixing -> no LDS needed.
__global__ __launch_bounds__(256) void layer_last_kernel(const float* __restrict__ xin,
                                                         float* __restrict__ xout,
                                                         const float* __restrict__ wl,
                                                         int d, int Tout) {
    int tx = threadIdx.x;
    int cg = __builtin_amdgcn_readfirstlane(threadIdx.y);
    int t  = blockIdx.x * 64 + tx;
    int b  = blockIdx.y;
    if (t >= Tout) return;
    const float* xi = xin + (size_t)(b * RCH) * TS + t;
    const float* wf = wl +        cg * 8;
    const float* wg = wl + 2048 + cg * 8;

    float accf[8], accg[8];
#pragma unroll
    for (int j = 0; j < 8; j++) { accf[j] = 0.f; accg[j] = 0.f; }
#pragma unroll 4
    for (int ic = 0; ic < 32; ic++) {
        float a = xi[ic * TS];
        float c = xi[ic * TS + d];
        const float* w0 = wf + ic * 64;
        const float* w1 = wg + ic * 64;
#pragma unroll
        for (int j = 0; j < 8; j++) accf[j] = fmaf(w0[j],      a, accf[j]);
#pragma unroll
        for (int j = 0; j < 8; j++) accf[j] = fmaf(w0[32 + j], c, accf[j]);
#pragma unroll
        for (int j = 0; j < 8; j++) accg[j] = fmaf(w1[j],      a, accg[j]);
#pragma unroll
        for (int j = 0; j < 8; j++) accg[j] = fmaf(w1[32 + j], c, accg[j]);
    }
    float* xo = xout + ((size_t)(b * RCH) + cg * 8) * TS + t;
#pragma unroll
    for (int j = 0; j < 8; j++)
        xo[j * TS] = tanh_fast(accf[j]) * sigmoid_fast(accg[j]);
}

// ---------------------------------------------------------------------------
// skip conv + relu, 32 outputs/thread
__global__ __launch_bounds__(256) void skip_kernel(const float* __restrict__ xin,
                                                   const float* __restrict__ sk,
                                                   float* __restrict__ h1) {
    int t = blockIdx.x * 256 + threadIdx.x;
    int sg = blockIdx.y;                     // 8 groups of 32
    int b = blockIdx.z;
    const float* xi = xin + (size_t)(b * RCH) * TS + t;
    const float* wb = sk + sg * 32;
    float acc[32];
#pragma unroll
    for (int j = 0; j < 32; j++) acc[j] = 0.f;
#pragma unroll 4
    for (int dc = 0; dc < 32; dc++) {
        float xv = xi[dc * TS];
        const float* w = wb + dc * 256;
#pragma unroll
        for (int j = 0; j < 32; j++) acc[j] = fmaf(w[j], xv, acc[j]);
    }
    float* ho = h1 + ((size_t)(b * 256) + sg * 32) * TOUT + t;
#pragma unroll
    for (int j = 0; j < 32; j++) ho[j * TOUT] = fmaxf(acc[j], 0.f);
}

// end1 + bias + relu, 32 outputs/thread
__global__ __launch_bounds__(256) void end1_kernel(const float* __restrict__ h1,
                                                   const float* __restrict__ e1t,
                                                   const float* __restrict__ b1,
                                                   float* __restrict__ e1) {
    int t = blockIdx.x * 256 + threadIdx.x;
    int eg = blockIdx.y;                     // 8 groups of 32
    int b = blockIdx.z;
    const float* hp = h1 + (size_t)(b * 256) * TOUT + t;
    const float* wb = e1t + eg * 32;
    float acc[32];
#pragma unroll
    for (int j = 0; j < 32; j++) acc[j] = b1[eg * 32 + j];
#pragma unroll 4
    for (int sc = 0; sc < 256; sc++) {
        float xv = hp[sc * TOUT];
        const float* w = wb + sc * 256;
#pragma unroll
        for (int j = 0; j < 32; j++) acc[j] = fmaf(w[j], xv, acc[j]);
    }
    float* ep = e1 + ((size_t)(b * 256) + eg * 32) * TOUT + t;
#pragma unroll
    for (int j = 0; j < 32; j++) ep[j * TOUT] = fmaxf(acc[j], 0.f);
}

// end2 + bias, transposed store, 32 outputs/thread
__global__ __launch_bounds__(256) void end2_kernel(const float* __restrict__ e1,
                                                   const float* __restrict__ e2t,
                                                   const float* __restrict__ b2,
                                                   float* __restrict__ out) {
    int t = blockIdx.x * 256 + threadIdx.x;
    int cg = blockIdx.y;                     // 8 groups of 32
    int b = blockIdx.z;
    const float* ep = e1 + (size_t)(b * 256) * TOUT + t;
    const float* wb = e2t + cg * 32;
    float acc[32];
#pragma unroll
    for (int j = 0; j < 32; j++) acc[j] = b2[cg * 32 + j];
#pragma unroll 4
    for (int ec = 0; ec < 256; ec++) {
        float xv = ep[ec * TOUT];
        const float* w = wb + ec * 256;
#pragma unroll
        for (int j = 0; j < 32; j++) acc[j] = fmaf(w[j], xv, acc[j]);
    }
    float* op = out + ((size_t)(b * TOUT + t)) * CLS + cg * 32;
#pragma unroll
    for (int j = 0; j < 8; j++)
        ((float4*)op)[j] = make_float4(acc[4*j], acc[4*j+1], acc[4*j+2], acc[4*j+3]);
}

// ---------------------------------------------------------------------------
extern "C" void kernel_launch(void* const* d_in, const int* in_sizes, int n_in,
                              void* d_out, int out_size, void* d_ws, size_t ws_size,
                              hipStream_t stream) {
    const float* x_input    = (const float*)d_in[0];
    const float* start_w    = (const float*)d_in[1];
    const float* filter_w   = (const float*)d_in[2];
    const float* gate_w     = (const float*)d_in[3];
    const float* residual_w = (const float*)d_in[4];
    const float* skip_w     = (const float*)d_in[5];
    const float* end1_w     = (const float*)d_in[6];
    const float* end1_b     = (const float*)d_in[7];
    const float* end2_w     = (const float*)d_in[8];
    const float* end2_b     = (const float*)d_in[9];
    float* ws  = (float*)d_ws;
    float* out = (float*)d_out;

    repack_kernel<<<dim3((352256 + 255) / 256), 256, 0, stream>>>(
        start_w, filter_w, gate_w, residual_w, skip_w, end1_w, end2_w, ws);

    start_kernel<<<dim3(32, 2, NB), 256, 0, stream>>>(
        x_input, ws + OFF_ST, ws + OFF_XA);

    float* bufs[2] = { ws + OFF_XA, ws + OFF_XB };
    int cur = 0;
    int Tin = T0;
    int cnt = 0;
    for (int bl = 0; bl < 4; bl++) {
        int dd = 1;
        for (int i = 0; i < 10; i++) {
            int Tout_l = Tin - dd;
            dim3 grid((Tout_l + 63) / 64, NB);
            dim3 blk(64, 4);
            if (cnt < 39) {
                layer_kernel<<<grid, blk, 0, stream>>>(
                    bufs[cur], bufs[cur ^ 1], ws + OFF_WBLOB + (size_t)cnt * 5120, dd, Tout_l);
            } else {
                layer_last_kernel<<<grid, blk, 0, stream>>>(
                    bufs[cur], bufs[cur ^ 1], ws + OFF_WBLOB + (size_t)cnt * 5120, dd, Tout_l);
            }
            cur ^= 1;
            Tin = Tout_l;
            dd *= 2;
            cnt++;
        }
    }
    // Tin == 4096; h of layer 39 in bufs[cur]

    skip_kernel<<<dim3(16, 8, NB), 256, 0, stream>>>(bufs[cur], ws + OFF_SK, ws + OFF_H1);
    end1_kernel<<<dim3(16, 8, NB), 256, 0, stream>>>(ws + OFF_H1, ws + OFF_E1T, end1_b, ws + OFF_E1);
    end2_kernel<<<dim3(16, 8, NB), 256, 0, stream>>>(ws + OFF_E1, ws + OFF_E2T, end2_b, out);
}